// Round 1
// baseline (3274.736 us; speedup 1.0000x reference)
//
#include <hip/hip_runtime.h>
#include <math.h>

#define T_LEN 32768
#define RC 64
#define GC 128
#define AC 80
#define TT 128
#define NLAYERS 30
#define KMAIN 272           // 3*64 dilated taps + 80 cond
#define SQRT_HALF 0.70710678118654752f
#define C30 0.18257418583505537f   // sqrt(1/30)

// ---------------- weight prep: transpose to [K][M] layouts ----------------
__global__ void prep_kernel(const float* __restrict__ Wd, const float* __restrict__ Wa,
                            const float* __restrict__ Ws, const float* __restrict__ Wr,
                            float* __restrict__ Wt_all, float* __restrict__ Wsr_all)
{
    int idx = blockIdx.x * 256 + threadIdx.x;
    const int n1 = NLAYERS * KMAIN * 128;
    if (idx < n1) {
        int o = idx & 127;
        int k = (idx >> 7) % KMAIN;
        int l = idx / (KMAIN * 128);
        float v;
        if (k < 192) {
            int tap = k >> 6, i = k & 63;
            v = Wd[((l * 128 + o) * 64 + i) * 3 + tap];
        } else {
            int a = k - 192;
            v = Wa[(l * 128 + o) * 80 + a];
        }
        Wt_all[idx] = v;
    } else {
        int j = idx - n1;
        if (j < NLAYERS * 64 * 128) {
            int m = j & 127;
            int i = (j >> 7) & 63;
            int l = j / (64 * 128);
            float v = (m < 64) ? Ws[(l * 64 + m) * 64 + i]
                               : Wr[(l * 64 + (m - 64)) * 64 + i];
            Wsr_all[j] = v;
        }
    }
}

// ---------------- upsampler ----------------
__global__ void cin_kernel(const float* __restrict__ c, const float* __restrict__ Wcin,
                           float* __restrict__ c1)
{
    int idx = blockIdx.x * 256 + threadIdx.x;
    if (idx >= 2 * AC * 128) return;
    int f = idx & 127;
    int o = (idx >> 7) % AC;
    int b = idx / (128 * AC);
    float acc = 0.f;
    for (int cc = 0; cc < AC; ++cc)
        acc = fmaf(Wcin[o * AC + cc], c[(b * AC + cc) * 128 + f], acc);
    c1[idx] = acc;
}

__global__ void up_kernel(const float* __restrict__ in, float* __restrict__ out,
                          const float* __restrict__ w9, int Win)
{
    int idx = blockIdx.x * 256 + threadIdx.x;
    int Wout = Win * 4;
    int total = 2 * AC * Wout;
    if (idx >= total) return;
    int t = idx % Wout;
    int bc = idx / Wout;
    const float* ip = in + bc * Win;
    float acc = 0.f;
#pragma unroll
    for (int j = 0; j < 9; ++j) {
        int q = t + j - 4;
        if (q >= 0 && q < Wout) acc = fmaf(w9[j], ip[q >> 2], acc);
    }
    out[idx] = acc;
}

// ---------------- first 1x1 conv ----------------
__global__ void first_kernel(const float* __restrict__ x, const float* __restrict__ Wf,
                             const float* __restrict__ bf, float* __restrict__ h)
{
    int idx = blockIdx.x * 256 + threadIdx.x;
    int t = idx & (T_LEN - 1);
    int i = (idx >> 15) & 63;
    int b = idx >> 21;
    h[idx] = fmaf(Wf[i], x[b * T_LEN + t], bf[i]);
}

// ---------------- fused WaveNet layer ----------------
// Block: 256 threads = 16x16; tile = 128 out-ch x 128 t; K = 272 (main) then 64 (epilogue).
__global__ __launch_bounds__(256, 2) void layer_kernel(
    const float* __restrict__ h_in, float* __restrict__ h_out,
    float* __restrict__ skips, const float* __restrict__ c_up,
    const float* __restrict__ Wt, const float* __restrict__ Wsr,
    const float* __restrict__ bd, const float* __restrict__ bs,
    const float* __restrict__ br, int dilation, int first_layer)
{
    __shared__ float sm[16384];            // 64 KiB
    float* A = sm;                         // [64][128]
    float* W = sm + 8192;                  // [64][128]
    const int tid = threadIdx.x;
    const int tx = tid & 15, ty = tid >> 4;
    const int b = blockIdx.y;
    const int t0 = blockIdx.x * TT;

    float acc[8][8];
#pragma unroll
    for (int m = 0; m < 8; ++m)
#pragma unroll
        for (int n = 0; n < 8; ++n) acc[m][n] = 0.f;

    for (int k0 = 0; k0 < KMAIN; k0 += 64) {
        const int klen = (KMAIN - k0 < 64) ? (KMAIN - k0) : 64;
        __syncthreads();
#pragma unroll
        for (int e = 0; e < 32; ++e) {
            int idx = e * 256 + tid;
            int r = idx >> 7, col = idx & 127;
            if (r < klen) {
                int k = k0 + r;
                float v;
                if (k < 192) {
                    int tap = k >> 6, i = k & 63;
                    int t = t0 + col + (tap - 1) * dilation;
                    v = (t >= 0 && t < T_LEN) ? h_in[(b * RC + i) * T_LEN + t] : 0.f;
                } else {
                    int a = k - 192;
                    v = c_up[(b * AC + a) * T_LEN + t0 + col];
                }
                A[r * 128 + col] = v;
                W[r * 128 + col] = Wt[k * 128 + col];
            }
        }
        __syncthreads();
#pragma unroll 2
        for (int kk = 0; kk < klen; ++kk) {
            float4 a0 = *(const float4*)&A[kk * 128 + tx * 8];
            float4 a1 = *(const float4*)&A[kk * 128 + tx * 8 + 4];
            float4 w0 = *(const float4*)&W[kk * 128 + ty * 8];
            float4 w1 = *(const float4*)&W[kk * 128 + ty * 8 + 4];
            float av[8] = {a0.x, a0.y, a0.z, a0.w, a1.x, a1.y, a1.z, a1.w};
            float wv[8] = {w0.x, w0.y, w0.z, w0.w, w1.x, w1.y, w1.z, w1.w};
#pragma unroll
            for (int m = 0; m < 8; ++m)
#pragma unroll
                for (int n = 0; n < 8; ++n)
                    acc[m][n] = fmaf(wv[m], av[n], acc[m][n]);
        }
    }
    __syncthreads();

    // g (+bd) -> LDS [128][128]
    float* g_ls = sm;
#pragma unroll
    for (int m = 0; m < 8; ++m) {
        float bdv = bd[ty * 8 + m];
#pragma unroll
        for (int n = 0; n < 8; ++n)
            g_ls[(ty * 8 + m) * 128 + tx * 8 + n] = acc[m][n] + bdv;
    }
    __syncthreads();

    // z = tanh(xa)*sigmoid(xb), into registers
    float zreg[32];
#pragma unroll
    for (int e = 0; e < 32; ++e) {
        int idx = e * 256 + tid;
        int i = idx >> 7, t = idx & 127;
        float xa = g_ls[i * 128 + t];
        float xb = g_ls[(i + 64) * 128 + t];
        float eh = __expf(-2.f * fabsf(xa));
        float th = (1.f - eh) / (1.f + eh);
        th = copysignf(th, xa);
        float sg = 1.f / (1.f + __expf(-xb));
        zreg[e] = th * sg;
    }
    __syncthreads();

    float* z_ls = sm;            // [64][128]
    float* W2 = sm + 8192;       // [64][128]
#pragma unroll
    for (int e = 0; e < 32; ++e) {
        int idx = e * 256 + tid;
        z_ls[idx] = zreg[e];
        W2[idx] = Wsr[idx];
    }
    __syncthreads();

    float acc2[8][8];
#pragma unroll
    for (int m = 0; m < 8; ++m)
#pragma unroll
        for (int n = 0; n < 8; ++n) acc2[m][n] = 0.f;
#pragma unroll 2
    for (int kk = 0; kk < 64; ++kk) {
        float4 a0 = *(const float4*)&z_ls[kk * 128 + tx * 8];
        float4 a1 = *(const float4*)&z_ls[kk * 128 + tx * 8 + 4];
        float4 w0 = *(const float4*)&W2[kk * 128 + ty * 8];
        float4 w1 = *(const float4*)&W2[kk * 128 + ty * 8 + 4];
        float av[8] = {a0.x, a0.y, a0.z, a0.w, a1.x, a1.y, a1.z, a1.w};
        float wv[8] = {w0.x, w0.y, w0.z, w0.w, w1.x, w1.y, w1.z, w1.w};
#pragma unroll
        for (int m = 0; m < 8; ++m)
#pragma unroll
            for (int n = 0; n < 8; ++n)
                acc2[m][n] = fmaf(wv[m], av[n], acc2[m][n]);
    }

    const int tb = t0 + tx * 8;
    if (ty < 8) {
#pragma unroll
        for (int m = 0; m < 8; ++m) {
            int sc_ = ty * 8 + m;
            float bv = bs[sc_];
            float* sp = skips + (b * 64 + sc_) * T_LEN + tb;
            if (first_layer) {
#pragma unroll
                for (int n = 0; n < 8; ++n) sp[n] = acc2[m][n] + bv;
            } else {
#pragma unroll
                for (int n = 0; n < 8; ++n) sp[n] += acc2[m][n] + bv;
            }
        }
    } else {
#pragma unroll
        for (int m = 0; m < 8; ++m) {
            int o = (ty - 8) * 8 + m;
            float bv = br[o];
            const float* hp = h_in + (b * RC + o) * T_LEN + tb;
            float* op = h_out + (b * RC + o) * T_LEN + tb;
#pragma unroll
            for (int n = 0; n < 8; ++n)
                op[n] = (acc2[m][n] + bv + hp[n]) * SQRT_HALF;
        }
    }
}

// ---------------- final head ----------------
__global__ __launch_bounds__(256) void final_kernel(
    const float* __restrict__ skips,
    const float* __restrict__ Wl1, const float* __restrict__ bl1,
    const float* __restrict__ Wl2, const float* __restrict__ bl2,
    float* __restrict__ y)
{
    __shared__ float w1[4096];
    __shared__ float w2[64];
    __shared__ float b1[64];
    int tid = threadIdx.x;
    for (int e = tid; e < 4096; e += 256) w1[e] = Wl1[e];
    if (tid < 64) { w2[tid] = Wl2[tid]; b1[tid] = bl1[tid]; }
    __syncthreads();
    int gid = blockIdx.x * 256 + tid;       // 0..65535
    int b = gid >> 15, tt = gid & (T_LEN - 1);
    float s[64];
#pragma unroll
    for (int i = 0; i < 64; ++i)
        s[i] = fmaxf(skips[(b * 64 + i) * T_LEN + tt] * C30, 0.f);
    float acc = bl2[0];
    for (int o = 0; o < 64; ++o) {
        float a = b1[o];
#pragma unroll
        for (int i = 0; i < 64; ++i) a = fmaf(w1[o * 64 + i], s[i], a);
        acc = fmaf(w2[o], fmaxf(a, 0.f), acc);
    }
    y[gid] = acc;
}

// ---------------- launch ----------------
extern "C" void kernel_launch(void* const* d_in, const int* in_sizes, int n_in,
                              void* d_out, int out_size, void* d_ws, size_t ws_size,
                              hipStream_t stream)
{
    const float* x       = (const float*)d_in[0];
    const float* c       = (const float*)d_in[1];
    const float* W_first = (const float*)d_in[2];
    const float* b_first = (const float*)d_in[3];
    const float* W_cin   = (const float*)d_in[4];
    const float* W_up    = (const float*)d_in[5];
    const float* Wd      = (const float*)d_in[6];
    const float* bd      = (const float*)d_in[7];
    const float* Wa      = (const float*)d_in[8];
    const float* Ws      = (const float*)d_in[9];
    const float* bs      = (const float*)d_in[10];
    const float* Wr      = (const float*)d_in[11];
    const float* br      = (const float*)d_in[12];
    const float* Wl1     = (const float*)d_in[13];
    const float* bl1     = (const float*)d_in[14];
    const float* Wl2     = (const float*)d_in[15];
    const float* bl2     = (const float*)d_in[16];

    float* ws = (float*)d_ws;
    size_t off = 0;
    float* c_up    = ws + off; off += (size_t)2 * AC * T_LEN;
    float* h0      = ws + off; off += (size_t)2 * RC * T_LEN;
    float* h1      = ws + off; off += (size_t)2 * RC * T_LEN;
    float* skips   = ws + off; off += (size_t)2 * RC * T_LEN;
    float* Wt_all  = ws + off; off += (size_t)NLAYERS * KMAIN * 128;
    float* Wsr_all = ws + off; off += (size_t)NLAYERS * 64 * 128;
    float* c1      = ws + off; off += (size_t)2 * AC * 128;
    float* u1      = ws + off; off += (size_t)2 * AC * 512;
    float* u2      = ws + off; off += (size_t)2 * AC * 2048;
    float* u3      = ws + off; off += (size_t)2 * AC * 8192;

    {
        int total = NLAYERS * KMAIN * 128 + NLAYERS * 64 * 128;
        prep_kernel<<<(total + 255) / 256, 256, 0, stream>>>(Wd, Wa, Ws, Wr, Wt_all, Wsr_all);
    }
    cin_kernel<<<(2 * AC * 128 + 255) / 256, 256, 0, stream>>>(c, W_cin, c1);
    up_kernel<<<(2 * AC * 512 + 255) / 256, 256, 0, stream>>>(c1, u1, W_up + 0, 128);
    up_kernel<<<(2 * AC * 2048 + 255) / 256, 256, 0, stream>>>(u1, u2, W_up + 9, 512);
    up_kernel<<<(2 * AC * 8192 + 255) / 256, 256, 0, stream>>>(u2, u3, W_up + 18, 2048);
    up_kernel<<<(2 * AC * 32768 + 255) / 256, 256, 0, stream>>>(u3, c_up, W_up + 27, 8192);
    first_kernel<<<(2 * RC * T_LEN) / 256, 256, 0, stream>>>(x, W_first, b_first, h0);

    float* hin = h0;
    float* hout = h1;
    for (int l = 0; l < NLAYERS; ++l) {
        int d = 1 << (l % 10);
        layer_kernel<<<dim3(T_LEN / TT, 2), 256, 0, stream>>>(
            hin, hout, skips, c_up,
            Wt_all + (size_t)l * KMAIN * 128, Wsr_all + (size_t)l * 64 * 128,
            bd + l * 128, bs + l * 64, br + l * 64, d, (l == 0) ? 1 : 0);
        float* tmp = hin; hin = hout; hout = tmp;
    }
    final_kernel<<<(2 * T_LEN) / 256, 256, 0, stream>>>(skips, Wl1, bl1, Wl2, bl2, (float*)d_out);
}

// Round 2
// 1656.290 us; speedup vs baseline: 1.9772x; 1.9772x over previous
//
#include <hip/hip_runtime.h>
#include <math.h>

#define T_LEN 32768
#define NLAYERS 30
#define SQRT_HALF 0.70710678118654752f
#define C30 0.18257418583505537f

typedef short short8 __attribute__((ext_vector_type(8)));
typedef short short4v __attribute__((ext_vector_type(4)));
typedef float float4v __attribute__((ext_vector_type(4)));
typedef unsigned short u16;

__device__ inline u16 rne_bf16(float f){
    unsigned u = __builtin_bit_cast(unsigned, f);
    u += 0x7fffu + ((u >> 16) & 1u);
    return (u16)(u >> 16);
}
__device__ inline float bf16_to_f32(u16 h){
    unsigned u = ((unsigned)h) << 16;
    return __builtin_bit_cast(float, u);
}
__device__ inline void split_bf16(float f, u16& hi, u16& lo){
    hi = rne_bf16(f);
    float r = f - bf16_to_f32(hi);
    lo = rne_bf16(r);
}

// ---------------- weight prep: fragment-ordered bf16 hi/lo ----------------
// Main GEMM A-frag: A[m][k], lane l: m = mb*16+(l&15), k = c*32+(l>>4)*8+j
// Flat: [layer][c(9)][mb(8)][lane(64)][j(8)]
__global__ void prep_wmain(const float* __restrict__ Wd, const float* __restrict__ Wa,
                           u16* __restrict__ WAh, u16* __restrict__ WAl)
{
    int idx = blockIdx.x * 256 + threadIdx.x;
    if (idx >= NLAYERS * 9 * 8 * 64) return;
    int lane = idx & 63;
    int mb = (idx >> 6) & 7;
    int cc = (idx >> 9) % 9;
    int l_ = (idx >> 9) / 9;
    int m = mb * 16 + (lane & 15);
    int kbase = cc * 32 + (lane >> 4) * 8;
    size_t off = (size_t)idx * 8;
#pragma unroll
    for (int j = 0; j < 8; ++j) {
        int k = kbase + j;
        float v = 0.f;
        if (k < 192) {
            int tap = k >> 6, i = k & 63;
            v = Wd[((size_t)(l_ * 128 + m) * 64 + i) * 3 + tap];
        } else if (k < 272) {
            v = Wa[(size_t)(l_ * 128 + m) * 80 + (k - 192)];
        }
        u16 hi, lo; split_bf16(v, hi, lo);
        WAh[off + j] = hi; WAl[off + j] = lo;
    }
}

// Second GEMM: W2[m2][k2], m2<64 -> Ws, else Wr. [layer][c(2)][mb(8)][lane][j]
__global__ void prep_wsr(const float* __restrict__ Ws, const float* __restrict__ Wr,
                         u16* __restrict__ W2h, u16* __restrict__ W2l)
{
    int idx = blockIdx.x * 256 + threadIdx.x;
    if (idx >= NLAYERS * 2 * 8 * 64) return;
    int lane = idx & 63;
    int mb = (idx >> 6) & 7;
    int cc = (idx >> 9) & 1;
    int l_ = idx >> 10;
    int m2 = mb * 16 + (lane & 15);
    int kbase = cc * 32 + (lane >> 4) * 8;
    size_t off = (size_t)idx * 8;
#pragma unroll
    for (int j = 0; j < 8; ++j) {
        int k2 = kbase + j;
        float v = (m2 < 64) ? Ws[(size_t)(l_ * 64 + m2) * 64 + k2]
                            : Wr[(size_t)(l_ * 64 + (m2 - 64)) * 64 + k2];
        u16 hi, lo; split_bf16(v, hi, lo);
        W2h[off + j] = hi; W2l[off + j] = lo;
    }
}

// ---------------- upsampler ----------------
__global__ void cin_kernel(const float* __restrict__ c, const float* __restrict__ Wcin,
                           float* __restrict__ c1)
{
    int idx = blockIdx.x * 256 + threadIdx.x;
    if (idx >= 2 * 80 * 128) return;
    int f = idx & 127;
    int o = (idx >> 7) % 80;
    int b = idx / (128 * 80);
    float acc = 0.f;
    for (int ch = 0; ch < 80; ++ch)
        acc = fmaf(Wcin[o * 80 + ch], c[(b * 80 + ch) * 128 + f], acc);
    c1[idx] = acc;
}

__global__ void up_kernel(const float* __restrict__ in, float* __restrict__ out,
                          const float* __restrict__ w9, int Win)
{
    int idx = blockIdx.x * 256 + threadIdx.x;
    int Wout = Win * 4;
    int total = 2 * 80 * Wout;
    if (idx >= total) return;
    int t = idx % Wout;
    int bc = idx / Wout;
    const float* ip = in + (size_t)bc * Win;
    float acc = 0.f;
#pragma unroll
    for (int j = 0; j < 9; ++j) {
        int q = t + j - 4;
        if (q >= 0 && q < Wout) acc = fmaf(w9[j], ip[q >> 2], acc);
    }
    out[idx] = acc;
}

// last stage: write c_up t-major [b][t][96] (pad 80..95 = 0), bf16 hi/lo planes
__global__ void upfinal_kernel(const float* __restrict__ u3, const float* __restrict__ w9,
                               u16* __restrict__ ch_, u16* __restrict__ cl_)
{
    int idx = blockIdx.x * 256 + threadIdx.x;
    if (idx >= 2 * T_LEN * 96) return;
    int a = idx % 96;
    int t = (idx / 96) & (T_LEN - 1);
    int b = idx / (96 * T_LEN);
    float acc = 0.f;
    if (a < 80) {
        const float* ip = u3 + ((size_t)(b * 80 + a)) * 8192;
#pragma unroll
        for (int j = 0; j < 9; ++j) {
            int q = t + j - 4;
            if (q >= 0 && q < T_LEN) acc = fmaf(w9[j], ip[q >> 2], acc);
        }
    }
    u16 hi, lo; split_bf16(acc, hi, lo);
    ch_[idx] = hi; cl_[idx] = lo;
}

// ---------------- first 1x1 conv -> h0 t-major hi/lo ----------------
__global__ void first_kernel(const float* __restrict__ x, const float* __restrict__ Wf,
                             const float* __restrict__ bf, u16* __restrict__ h0h,
                             u16* __restrict__ h0l)
{
    int idx = blockIdx.x * 256 + threadIdx.x;   // (b*T+t)*64 + i
    int i = idx & 63;
    int bt = idx >> 6;
    float v = fmaf(Wf[i], x[bt], bf[i]);
    u16 hi, lo; split_bf16(v, hi, lo);
    h0h[idx] = hi; h0l[idx] = lo;
}

// ---------------- fused WaveNet layer (MFMA bf16x3) ----------------
// Block 256 = 4 waves. Wave tile: 128 out-ch x 32 t. Block tile: 128 x 128 t.
__global__ __launch_bounds__(256, 2) void layer_kernel(
    const u16* __restrict__ h_hi, const u16* __restrict__ h_lo,
    u16* __restrict__ ho_hi, u16* __restrict__ ho_lo,
    float* __restrict__ skips,
    const u16* __restrict__ cup_hi, const u16* __restrict__ cup_lo,
    const u16* __restrict__ WAh, const u16* __restrict__ WAl,
    const u16* __restrict__ W2h, const u16* __restrict__ W2l,
    const float* __restrict__ bd, const float* __restrict__ bs,
    const float* __restrict__ br, int dil, int first_layer)
{
    __shared__ char zsm[32768];                 // 4 waves x (hi 4KB + lo 4KB)
    const int tid = threadIdx.x;
    const int l  = tid & 63;
    const int w  = tid >> 6;
    const int lr = l & 15;                       // t-lane within 16
    const int lg = l >> 4;                       // k-group 0..3
    const int b  = blockIdx.y;
    const int n0 = blockIdx.x * 128 + w * 32;
    char* zb = zsm + w * 8192;

    float4v acc[8][2];
#pragma unroll
    for (int mb = 0; mb < 8; ++mb)
#pragma unroll
        for (int nb = 0; nb < 2; ++nb) acc[mb][nb] = (float4v)0.f;

    const short8 zero8 = (short8)0;

    // ---- main GEMM: K = 288 (192 dilated taps + 80 cond + 16 pad), 9 chunks of 32
#pragma unroll
    for (int cc = 0; cc < 9; ++cc) {
        short8 bh[2], bl[2];
        if (cc < 6) {
            const int tap = cc >> 1;
            const int i0 = (cc & 1) * 32 + lg * 8;
#pragma unroll
            for (int nb = 0; nb < 2; ++nb) {
                int t = n0 + nb * 16 + lr + (tap - 1) * dil;
                if ((unsigned)t < (unsigned)T_LEN) {
                    size_t off = ((size_t)b * T_LEN + t) * 64 + i0;
                    bh[nb] = *(const short8*)(h_hi + off);
                    bl[nb] = *(const short8*)(h_lo + off);
                } else { bh[nb] = zero8; bl[nb] = zero8; }
            }
        } else {
            const int a0 = (cc - 6) * 32 + lg * 8;
#pragma unroll
            for (int nb = 0; nb < 2; ++nb) {
                int t = n0 + nb * 16 + lr;
                size_t off = ((size_t)b * T_LEN + t) * 96 + a0;
                bh[nb] = *(const short8*)(cup_hi + off);
                bl[nb] = *(const short8*)(cup_lo + off);
            }
        }
#pragma unroll
        for (int mb = 0; mb < 8; ++mb) {
            size_t woff = (((size_t)cc * 8 + mb) * 64 + l) * 8;
            short8 ah = *(const short8*)(WAh + woff);
            short8 al = *(const short8*)(WAl + woff);
#pragma unroll
            for (int nb = 0; nb < 2; ++nb) {
                acc[mb][nb] = __builtin_amdgcn_mfma_f32_16x16x32_bf16(ah, bh[nb], acc[mb][nb], 0, 0, 0);
                acc[mb][nb] = __builtin_amdgcn_mfma_f32_16x16x32_bf16(ah, bl[nb], acc[mb][nb], 0, 0, 0);
                acc[mb][nb] = __builtin_amdgcn_mfma_f32_16x16x32_bf16(al, bh[nb], acc[mb][nb], 0, 0, 0);
            }
        }
    }

    // ---- gating: z[i] = tanh(g[i]) * sigmoid(g[i+64]); write hi/lo to swizzled LDS
#pragma unroll
    for (int mb = 0; mb < 4; ++mb) {
        const float4v bda = *(const float4v*)(bd + mb * 16 + lg * 4);
        const float4v bdb = *(const float4v*)(bd + 64 + mb * 16 + lg * 4);
#pragma unroll
        for (int nb = 0; nb < 2; ++nb) {
            int t = nb * 16 + lr;                 // 0..31 local
            short4v zhv, zlv;
#pragma unroll
            for (int r = 0; r < 4; ++r) {
                float xa = acc[mb][nb][r] + bda[r];
                float xb = acc[mb + 4][nb][r] + bdb[r];
                float e2 = __expf(2.f * xa);
                float th = 1.f - 2.f * __builtin_amdgcn_rcpf(e2 + 1.f);
                float sg = __builtin_amdgcn_rcpf(1.f + __expf(-xb));
                u16 hi, lo; split_bf16(th * sg, hi, lo);
                zhv[r] = (short)hi; zlv[r] = (short)lo;
            }
            unsigned byteoff = (unsigned)((t * 64 + mb * 16 + lg * 4) * 2) ^ ((unsigned)(t & 7) << 4);
            *(short4v*)(zb + byteoff) = zhv;
            *(short4v*)(zb + 4096 + byteoff) = zlv;
        }
    }
    __syncthreads();   // conservative: ensure LDS writes visible before reads

    // ---- second GEMM: [64 skip + 64 res] x z, K = 64 (2 chunks)
    float4v acc2[8][2];
#pragma unroll
    for (int mb = 0; mb < 8; ++mb)
#pragma unroll
        for (int nb = 0; nb < 2; ++nb) acc2[mb][nb] = (float4v)0.f;

#pragma unroll
    for (int c2 = 0; c2 < 2; ++c2) {
        short8 b2h[2], b2l[2];
#pragma unroll
        for (int nb = 0; nb < 2; ++nb) {
            int t = nb * 16 + lr;
            unsigned k0 = (unsigned)(c2 * 32 + lg * 8);
            unsigned byteoff = (unsigned)((t * 64 + k0) * 2) ^ ((unsigned)(t & 7) << 4);
            b2h[nb] = *(const short8*)(zb + byteoff);
            b2l[nb] = *(const short8*)(zb + 4096 + byteoff);
        }
#pragma unroll
        for (int mb = 0; mb < 8; ++mb) {
            size_t woff = (((size_t)c2 * 8 + mb) * 64 + l) * 8;
            short8 ah = *(const short8*)(W2h + woff);
            short8 al = *(const short8*)(W2l + woff);
#pragma unroll
            for (int nb = 0; nb < 2; ++nb) {
                acc2[mb][nb] = __builtin_amdgcn_mfma_f32_16x16x32_bf16(ah, b2h[nb], acc2[mb][nb], 0, 0, 0);
                acc2[mb][nb] = __builtin_amdgcn_mfma_f32_16x16x32_bf16(ah, b2l[nb], acc2[mb][nb], 0, 0, 0);
                acc2[mb][nb] = __builtin_amdgcn_mfma_f32_16x16x32_bf16(al, b2h[nb], acc2[mb][nb], 0, 0, 0);
            }
        }
    }

    // ---- epilogue: skips RMW (fp32), residual h_out (bf16 hi/lo)
#pragma unroll
    for (int mb = 0; mb < 8; ++mb) {
        int ch0 = (mb & 3) * 16 + lg * 4;
        if (mb < 4) {
            const float4v bsv = *(const float4v*)(bs + ch0);
#pragma unroll
            for (int nb = 0; nb < 2; ++nb) {
                int t = n0 + nb * 16 + lr;
                float* sp = skips + ((size_t)b * T_LEN + t) * 64 + ch0;
                float4v v = acc2[mb][nb] + bsv;
                if (!first_layer) v = v + *(const float4v*)sp;
                *(float4v*)sp = v;
            }
        } else {
            const float4v brv = *(const float4v*)(br + ch0);
#pragma unroll
            for (int nb = 0; nb < 2; ++nb) {
                int t = n0 + nb * 16 + lr;
                size_t off = ((size_t)b * T_LEN + t) * 64 + ch0;
                short4v hv = *(const short4v*)(h_hi + off);
                short4v lv = *(const short4v*)(h_lo + off);
                short4v ohv, olv;
#pragma unroll
                for (int r = 0; r < 4; ++r) {
                    float hr = bf16_to_f32((u16)hv[r]) + bf16_to_f32((u16)lv[r]);
                    float xo = (acc2[mb][nb][r] + brv[r] + hr) * SQRT_HALF;
                    u16 hi, lo; split_bf16(xo, hi, lo);
                    ohv[r] = (short)hi; olv[r] = (short)lo;
                }
                *(short4v*)(ho_hi + off) = ohv;
                *(short4v*)(ho_lo + off) = olv;
            }
        }
    }
}

// ---------------- final head ----------------
__global__ __launch_bounds__(256) void final_kernel(
    const float* __restrict__ skips,
    const float* __restrict__ Wl1, const float* __restrict__ bl1,
    const float* __restrict__ Wl2, const float* __restrict__ bl2,
    float* __restrict__ y)
{
    __shared__ float w1[4096];
    __shared__ float w2[64];
    __shared__ float b1[64];
    int tid = threadIdx.x;
    for (int e = tid; e < 4096; e += 256) w1[e] = Wl1[e];
    if (tid < 64) { w2[tid] = Wl2[tid]; b1[tid] = bl1[tid]; }
    __syncthreads();
    int gid = blockIdx.x * 256 + tid;            // b*T + t
    const float* sp = skips + (size_t)gid * 64;
    float s[64];
#pragma unroll
    for (int i = 0; i < 64; ++i)
        s[i] = fmaxf(sp[i] * C30, 0.f);
    float acc = bl2[0];
    for (int o = 0; o < 64; ++o) {
        float a = b1[o];
#pragma unroll
        for (int i = 0; i < 64; ++i) a = fmaf(w1[o * 64 + i], s[i], a);
        acc = fmaf(w2[o], fmaxf(a, 0.f), acc);
    }
    y[gid] = acc;
}

// ---------------- launch ----------------
extern "C" void kernel_launch(void* const* d_in, const int* in_sizes, int n_in,
                              void* d_out, int out_size, void* d_ws, size_t ws_size,
                              hipStream_t stream)
{
    const float* x       = (const float*)d_in[0];
    const float* c       = (const float*)d_in[1];
    const float* W_first = (const float*)d_in[2];
    const float* b_first = (const float*)d_in[3];
    const float* W_cin   = (const float*)d_in[4];
    const float* W_up    = (const float*)d_in[5];
    const float* Wd      = (const float*)d_in[6];
    const float* bd      = (const float*)d_in[7];
    const float* Wa      = (const float*)d_in[8];
    const float* Ws      = (const float*)d_in[9];
    const float* bs      = (const float*)d_in[10];
    const float* Wr      = (const float*)d_in[11];
    const float* br      = (const float*)d_in[12];
    const float* Wl1     = (const float*)d_in[13];
    const float* bl1     = (const float*)d_in[14];
    const float* Wl2     = (const float*)d_in[15];
    const float* bl2     = (const float*)d_in[16];

    char* base = (char*)d_ws;
    size_t off = 0;
    auto alloc = [&](size_t bytes) { char* p = base + off; off += (bytes + 255) & ~(size_t)255; return p; };

    u16* cup_hi = (u16*)alloc((size_t)2 * T_LEN * 96 * 2);
    u16* cup_lo = (u16*)alloc((size_t)2 * T_LEN * 96 * 2);
    u16* h0_hi  = (u16*)alloc((size_t)2 * T_LEN * 64 * 2);
    u16* h0_lo  = (u16*)alloc((size_t)2 * T_LEN * 64 * 2);
    u16* h1_hi  = (u16*)alloc((size_t)2 * T_LEN * 64 * 2);
    u16* h1_lo  = (u16*)alloc((size_t)2 * T_LEN * 64 * 2);
    float* skips = (float*)alloc((size_t)2 * T_LEN * 64 * 4);
    // scratch region: first used by upsample chain, then reused for weight frags
    char* S = alloc(7000000);
    float* c1 = (float*)(S);
    float* u1 = (float*)(S + 81920);
    float* u2 = (float*)(S + 409600);
    float* u3 = (float*)(S + 1720320);
    // after upfinal completes, prep kernels overwrite S with weight fragments
    u16* WAh = (u16*)(S);
    u16* WAl = (u16*)(S + 2764800);
    u16* W2h = (u16*)(S + 5529600);
    u16* W2l = (u16*)(S + 6021120);

    // upsample chain (fp32), finishing with t-major bf16 hi/lo c_up
    cin_kernel<<<(2 * 80 * 128 + 255) / 256, 256, 0, stream>>>(c, W_cin, c1);
    up_kernel<<<(2 * 80 * 512 + 255) / 256, 256, 0, stream>>>(c1, u1, W_up + 0, 128);
    up_kernel<<<(2 * 80 * 2048 + 255) / 256, 256, 0, stream>>>(u1, u2, W_up + 9, 512);
    up_kernel<<<(2 * 80 * 8192 + 255) / 256, 256, 0, stream>>>(u2, u3, W_up + 18, 2048);
    upfinal_kernel<<<(2 * T_LEN * 96 + 255) / 256, 256, 0, stream>>>(u3, W_up + 27, cup_hi, cup_lo);

    // weight prep (reuses S after upsample chain is done; stream-ordered)
    prep_wmain<<<(NLAYERS * 9 * 8 * 64 + 255) / 256, 256, 0, stream>>>(Wd, Wa, WAh, WAl);
    prep_wsr<<<(NLAYERS * 2 * 8 * 64 + 255) / 256, 256, 0, stream>>>(Ws, Wr, W2h, W2l);

    first_kernel<<<(2 * T_LEN * 64) / 256, 256, 0, stream>>>(x, W_first, b_first, h0_hi, h0_lo);

    u16* hin_hi = h0_hi; u16* hin_lo = h0_lo;
    u16* hout_hi = h1_hi; u16* hout_lo = h1_lo;
    for (int l_ = 0; l_ < NLAYERS; ++l_) {
        int d = 1 << (l_ % 10);
        layer_kernel<<<dim3(T_LEN / 128, 2), 256, 0, stream>>>(
            hin_hi, hin_lo, hout_hi, hout_lo, skips, cup_hi, cup_lo,
            WAh + (size_t)l_ * 36864, WAl + (size_t)l_ * 36864,
            W2h + (size_t)l_ * 8192, W2l + (size_t)l_ * 8192,
            bd + l_ * 128, bs + l_ * 64, br + l_ * 64, d, (l_ == 0) ? 1 : 0);
        u16* th = hin_hi; u16* tl = hin_lo;
        hin_hi = hout_hi; hin_lo = hout_lo;
        hout_hi = th; hout_lo = tl;
    }
    final_kernel<<<(2 * T_LEN) / 256, 256, 0, stream>>>(skips, Wl1, bl1, Wl2, bl2, (float*)d_out);
}

// Round 3
// 1102.193 us; speedup vs baseline: 2.9711x; 1.5027x over previous
//
#include <hip/hip_runtime.h>
#include <math.h>

#define T_LEN 32768
#define NLAYERS 30
#define SQRT_HALF 0.70710678118654752f
#define C30 0.18257418583505537f

typedef short short8 __attribute__((ext_vector_type(8)));
typedef short short4v __attribute__((ext_vector_type(4)));
typedef float float4v __attribute__((ext_vector_type(4)));
typedef unsigned short u16;

__device__ inline u16 rne_bf16(float f){
    unsigned u = __builtin_bit_cast(unsigned, f);
    u += 0x7fffu + ((u >> 16) & 1u);
    return (u16)(u >> 16);
}
__device__ inline float bf16_to_f32(u16 h){
    unsigned u = ((unsigned)h) << 16;
    return __builtin_bit_cast(float, u);
}
__device__ inline void split_bf16(float f, u16& hi, u16& lo){
    hi = rne_bf16(f);
    float r = f - bf16_to_f32(hi);
    lo = rne_bf16(r);
}

// ---------------- weight prep: combined chunk layout ----------------
// WA chunk layout (u16): [layer][cc(9)][plane(2)][mb(8)][lane(64)][j(8)]  (16KB/chunk)
// A-frag: m = mb*16+(lane&15), k = cc*32+(lane>>4)*8+j
__global__ void prep_wmain(const float* __restrict__ Wd, const float* __restrict__ Wa,
                           u16* __restrict__ WA)
{
    int idx = blockIdx.x * 256 + threadIdx.x;
    if (idx >= NLAYERS * 9 * 8 * 64) return;
    int lane = idx & 63;
    int mb = (idx >> 6) & 7;
    int cc = (idx >> 9) % 9;
    int l_ = (idx >> 9) / 9;
    int m = mb * 16 + (lane & 15);
    int kbase = cc * 32 + (lane >> 4) * 8;
    size_t base = ((size_t)(l_ * 9 + cc)) * 8192 + mb * 512 + lane * 8;
#pragma unroll
    for (int j = 0; j < 8; ++j) {
        int k = kbase + j;
        float v = 0.f;
        if (k < 192) {
            int tap = k >> 6, i = k & 63;
            v = Wd[((size_t)(l_ * 128 + m) * 64 + i) * 3 + tap];
        } else if (k < 272) {
            v = Wa[(size_t)(l_ * 128 + m) * 80 + (k - 192)];
        }
        u16 hi, lo; split_bf16(v, hi, lo);
        WA[base + j] = hi; WA[base + 4096 + j] = lo;
    }
}

// W2 chunk layout (u16): [layer][c2(2)][plane(2)][mb(8)][lane(64)][j(8)]
__global__ void prep_wsr(const float* __restrict__ Ws, const float* __restrict__ Wr,
                         u16* __restrict__ W2)
{
    int idx = blockIdx.x * 256 + threadIdx.x;
    if (idx >= NLAYERS * 2 * 8 * 64) return;
    int lane = idx & 63;
    int mb = (idx >> 6) & 7;
    int cc = (idx >> 9) & 1;
    int l_ = idx >> 10;
    int m2 = mb * 16 + (lane & 15);
    int kbase = cc * 32 + (lane >> 4) * 8;
    size_t base = ((size_t)(l_ * 2 + cc)) * 8192 + mb * 512 + lane * 8;
#pragma unroll
    for (int j = 0; j < 8; ++j) {
        int k2 = kbase + j;
        float v = (m2 < 64) ? Ws[(size_t)(l_ * 64 + m2) * 64 + k2]
                            : Wr[(size_t)(l_ * 64 + (m2 - 64)) * 64 + k2];
        u16 hi, lo; split_bf16(v, hi, lo);
        W2[base + j] = hi; W2[base + 4096 + j] = lo;
    }
}

// ---------------- upsampler (t-major) ----------------
// c1[b][f(128)][80]
__global__ void cin_kernel(const float* __restrict__ c, const float* __restrict__ Wcin,
                           float* __restrict__ c1)
{
    int idx = blockIdx.x * 256 + threadIdx.x;
    if (idx >= 2 * 128 * 80) return;
    int o = idx % 80;
    int f = (idx / 80) & 127;
    int b = idx / (80 * 128);
    float acc = 0.f;
    for (int ch = 0; ch < 80; ++ch)
        acc = fmaf(Wcin[o * 80 + ch], c[(b * 80 + ch) * 128 + f], acc);
    c1[idx] = acc;
}

// in [b][Win][80] -> out [b][4*Win][80]
__global__ void up_kernel(const float* __restrict__ in, float* __restrict__ out,
                          const float* __restrict__ w9, int Win)
{
    int idx = blockIdx.x * 256 + threadIdx.x;
    int Wout = Win * 4;
    int total = 2 * Wout * 80;
    if (idx >= total) return;
    int a = idx % 80;
    int t = (idx / 80) % Wout;
    int b = idx / (80 * Wout);
    const float* ip = in + (size_t)b * Win * 80 + a;
    float acc = 0.f;
#pragma unroll
    for (int j = 0; j < 9; ++j) {
        int q = t + j - 4;
        if (q >= 0 && q < Wout) acc = fmaf(w9[j], ip[(size_t)(q >> 2) * 80], acc);
    }
    out[idx] = acc;
}

// u3 [b][8192][80] -> c_up t-major [b][t][96] bf16 hi/lo (pad 80..95 = 0)
__global__ void upfinal_kernel(const float* __restrict__ u3, const float* __restrict__ w9,
                               u16* __restrict__ ch_, u16* __restrict__ cl_)
{
    int idx = blockIdx.x * 256 + threadIdx.x;
    if (idx >= 2 * T_LEN * 96) return;
    int a = idx % 96;
    int t = (idx / 96) & (T_LEN - 1);
    int b = idx / (96 * T_LEN);
    float acc = 0.f;
    if (a < 80) {
        const float* ip = u3 + (size_t)b * 8192 * 80 + a;
#pragma unroll
        for (int j = 0; j < 9; ++j) {
            int q = t + j - 4;
            if (q >= 0 && q < T_LEN) acc = fmaf(w9[j], ip[(size_t)(q >> 2) * 80], acc);
        }
    }
    u16 hi, lo; split_bf16(acc, hi, lo);
    ch_[idx] = hi; cl_[idx] = lo;
}

// ---------------- first 1x1 conv -> h0 t-major hi/lo ----------------
__global__ void first_kernel(const float* __restrict__ x, const float* __restrict__ Wf,
                             const float* __restrict__ bf, u16* __restrict__ h0h,
                             u16* __restrict__ h0l)
{
    int idx = blockIdx.x * 256 + threadIdx.x;   // (b*T+t)*64 + i
    int i = idx & 63;
    int bt = idx >> 6;
    float v = fmaf(Wf[i], x[bt], bf[i]);
    u16 hi, lo; split_bf16(v, hi, lo);
    h0h[idx] = hi; h0l[idx] = lo;
}

// ---------------- fused WaveNet layer (MFMA bf16x3, LDS-staged weights) ----------------
// Block 256 = 4 waves. Wave tile: 128 out-ch x 32 t. Block tile: 128 x 128 t.
__global__ __launch_bounds__(256, 2) void layer_kernel(
    const u16* __restrict__ h_hi, const u16* __restrict__ h_lo,
    u16* __restrict__ ho_hi, u16* __restrict__ ho_lo,
    float* __restrict__ skips,
    const u16* __restrict__ cup_hi, const u16* __restrict__ cup_lo,
    const u16* __restrict__ WA, const u16* __restrict__ W2,
    const float* __restrict__ bd, const float* __restrict__ bs,
    const float* __restrict__ br, int dil, int first_layer)
{
    __shared__ char wsm[32768];                 // weight double buffer (2 x 16KB)
    __shared__ char zsm[32768];                 // 4 waves x 8KB z zones
    const int tid = threadIdx.x;
    const int l  = tid & 63;
    const int w  = tid >> 6;
    const int lr = l & 15;
    const int lg = l >> 4;
    const int b  = blockIdx.y;
    // XCD-chunked swizzle: 256 tiles = 8 XCDs x 32 contiguous tiles
    const int bx = blockIdx.x;
    const int tile = ((bx & 7) << 5) | (bx >> 3);
    const int n0 = tile * 128 + w * 32;
    char* zb = zsm + w * 8192;

    auto load_st = [&](const u16* p, short8* r){
#pragma unroll
        for (int it = 0; it < 4; ++it)
            r[it] = *(const short8*)(p + (size_t)tid * 8 + it * 2048);
    };
    auto write_st = [&](char* buf, short8* r){
#pragma unroll
        for (int it = 0; it < 4; ++it)
            *(short8*)(buf + tid * 16 + it * 4096) = r[it];
    };

    float4v acc[8][2];
#pragma unroll
    for (int mb = 0; mb < 8; ++mb)
#pragma unroll
        for (int nb = 0; nb < 2; ++nb) acc[mb][nb] = (float4v)0.f;

    const short8 zero8 = (short8)0;
    short8 wst[4];

    // prologue: stage chunk 0
    load_st(WA, wst);
    write_st(wsm, wst);

    // ---- main GEMM: 9 chunks of K=32 (192 taps + 80 cond + 16 pad)
#pragma unroll
    for (int cc = 0; cc < 9; ++cc) {
        __syncthreads();
        char* cbuf = wsm + (cc & 1) * 16384;
        // b-frags (issued first so their waits keep stage loads in flight)
        short8 bh[2], bl[2];
        if (cc < 6) {
            const int tap = cc >> 1;
            const int i0 = (cc & 1) * 32 + lg * 8;
#pragma unroll
            for (int nb = 0; nb < 2; ++nb) {
                int t = n0 + nb * 16 + lr + (tap - 1) * dil;
                if ((unsigned)t < (unsigned)T_LEN) {
                    size_t off = ((size_t)b * T_LEN + t) * 64 + i0;
                    bh[nb] = *(const short8*)(h_hi + off);
                    bl[nb] = *(const short8*)(h_lo + off);
                } else { bh[nb] = zero8; bl[nb] = zero8; }
            }
        } else {
            const int a0 = (cc - 6) * 32 + lg * 8;
#pragma unroll
            for (int nb = 0; nb < 2; ++nb) {
                int t = n0 + nb * 16 + lr;
                size_t off = ((size_t)b * T_LEN + t) * 96 + a0;
                bh[nb] = *(const short8*)(cup_hi + off);
                bl[nb] = *(const short8*)(cup_lo + off);
            }
        }
        // stage next chunk (9th stages W2 chunk 0)
        const u16* nxt = (cc < 8) ? (WA + (size_t)(cc + 1) * 8192) : W2;
        load_st(nxt, wst);
        // compute
#pragma unroll
        for (int mb = 0; mb < 8; ++mb) {
            short8 ah = *(const short8*)(cbuf + mb * 1024 + l * 16);
            short8 al = *(const short8*)(cbuf + 8192 + mb * 1024 + l * 16);
#pragma unroll
            for (int nb = 0; nb < 2; ++nb) {
                acc[mb][nb] = __builtin_amdgcn_mfma_f32_16x16x32_bf16(ah, bh[nb], acc[mb][nb], 0, 0, 0);
                acc[mb][nb] = __builtin_amdgcn_mfma_f32_16x16x32_bf16(ah, bl[nb], acc[mb][nb], 0, 0, 0);
                acc[mb][nb] = __builtin_amdgcn_mfma_f32_16x16x32_bf16(al, bh[nb], acc[mb][nb], 0, 0, 0);
            }
        }
        write_st(wsm + ((cc + 1) & 1) * 16384, wst);
    }

    // ---- gating: z = tanh(xa)*sigmoid(xb) -> per-wave swizzled LDS (no barrier needed)
#pragma unroll
    for (int mb = 0; mb < 4; ++mb) {
        const float4v bda = *(const float4v*)(bd + mb * 16 + lg * 4);
        const float4v bdb = *(const float4v*)(bd + 64 + mb * 16 + lg * 4);
#pragma unroll
        for (int nb = 0; nb < 2; ++nb) {
            int t = nb * 16 + lr;                 // 0..31 local
            short4v zhv, zlv;
#pragma unroll
            for (int r = 0; r < 4; ++r) {
                float xa = acc[mb][nb][r] + bda[r];
                float xb = acc[mb + 4][nb][r] + bdb[r];
                float e2 = __expf(2.f * xa);
                float th = 1.f - 2.f * __builtin_amdgcn_rcpf(e2 + 1.f);
                float sg = __builtin_amdgcn_rcpf(1.f + __expf(-xb));
                u16 hi, lo; split_bf16(th * sg, hi, lo);
                zhv[r] = (short)hi; zlv[r] = (short)lo;
            }
            unsigned byteoff = (unsigned)((t * 64 + mb * 16 + lg * 4) * 2) ^ ((unsigned)(t & 7) << 4);
            *(short4v*)(zb + byteoff) = zhv;
            *(short4v*)(zb + 4096 + byteoff) = zlv;
        }
    }

    // ---- second GEMM: K=64, 2 chunks (chunks 9,10 of the stage pipeline)
    float4v acc2[8][2];
#pragma unroll
    for (int mb = 0; mb < 8; ++mb)
#pragma unroll
        for (int nb = 0; nb < 2; ++nb) acc2[mb][nb] = (float4v)0.f;

#pragma unroll
    for (int c2 = 0; c2 < 2; ++c2) {
        __syncthreads();
        char* cbuf = wsm + ((9 + c2) & 1) * 16384;
        short8 b2h[2], b2l[2];
#pragma unroll
        for (int nb = 0; nb < 2; ++nb) {
            int t = nb * 16 + lr;
            unsigned k0 = (unsigned)(c2 * 32 + lg * 8);
            unsigned byteoff = (unsigned)((t * 64 + k0) * 2) ^ ((unsigned)(t & 7) << 4);
            b2h[nb] = *(const short8*)(zb + byteoff);
            b2l[nb] = *(const short8*)(zb + 4096 + byteoff);
        }
        if (c2 == 0) load_st(W2 + 8192, wst);
#pragma unroll
        for (int mb = 0; mb < 8; ++mb) {
            short8 ah = *(const short8*)(cbuf + mb * 1024 + l * 16);
            short8 al = *(const short8*)(cbuf + 8192 + mb * 1024 + l * 16);
#pragma unroll
            for (int nb = 0; nb < 2; ++nb) {
                acc2[mb][nb] = __builtin_amdgcn_mfma_f32_16x16x32_bf16(ah, b2h[nb], acc2[mb][nb], 0, 0, 0);
                acc2[mb][nb] = __builtin_amdgcn_mfma_f32_16x16x32_bf16(ah, b2l[nb], acc2[mb][nb], 0, 0, 0);
                acc2[mb][nb] = __builtin_amdgcn_mfma_f32_16x16x32_bf16(al, b2h[nb], acc2[mb][nb], 0, 0, 0);
            }
        }
        if (c2 == 0) write_st(wsm, wst);
    }

    // ---- epilogue: skips RMW (fp32), residual h_out (bf16 hi/lo)
#pragma unroll
    for (int mb = 0; mb < 8; ++mb) {
        int ch0 = (mb & 3) * 16 + lg * 4;
        if (mb < 4) {
            const float4v bsv = *(const float4v*)(bs + ch0);
#pragma unroll
            for (int nb = 0; nb < 2; ++nb) {
                int t = n0 + nb * 16 + lr;
                float* sp = skips + ((size_t)b * T_LEN + t) * 64 + ch0;
                float4v v = acc2[mb][nb] + bsv;
                if (!first_layer) v = v + *(const float4v*)sp;
                *(float4v*)sp = v;
            }
        } else {
            const float4v brv = *(const float4v*)(br + ch0);
#pragma unroll
            for (int nb = 0; nb < 2; ++nb) {
                int t = n0 + nb * 16 + lr;
                size_t off = ((size_t)b * T_LEN + t) * 64 + ch0;
                short4v hv = *(const short4v*)(h_hi + off);
                short4v lv = *(const short4v*)(h_lo + off);
                short4v ohv, olv;
#pragma unroll
                for (int r = 0; r < 4; ++r) {
                    float hr = bf16_to_f32((u16)hv[r]) + bf16_to_f32((u16)lv[r]);
                    float xo = (acc2[mb][nb][r] + brv[r] + hr) * SQRT_HALF;
                    u16 hi, lo; split_bf16(xo, hi, lo);
                    ohv[r] = (short)hi; olv[r] = (short)lo;
                }
                *(short4v*)(ho_hi + off) = ohv;
                *(short4v*)(ho_lo + off) = olv;
            }
        }
    }
}

// ---------------- final head ----------------
__global__ __launch_bounds__(256) void final_kernel(
    const float* __restrict__ skips,
    const float* __restrict__ Wl1, const float* __restrict__ bl1,
    const float* __restrict__ Wl2, const float* __restrict__ bl2,
    float* __restrict__ y)
{
    __shared__ float w1[4096];
    __shared__ float w2[64];
    __shared__ float b1[64];
    int tid = threadIdx.x;
    for (int e = tid; e < 4096; e += 256) w1[e] = Wl1[e];
    if (tid < 64) { w2[tid] = Wl2[tid]; b1[tid] = bl1[tid]; }
    __syncthreads();
    int gid = blockIdx.x * 256 + tid;            // b*T + t
    const float* sp = skips + (size_t)gid * 64;
    float s[64];
#pragma unroll
    for (int i = 0; i < 64; ++i)
        s[i] = fmaxf(sp[i] * C30, 0.f);
    float acc = bl2[0];
    for (int o = 0; o < 64; ++o) {
        float a = b1[o];
#pragma unroll
        for (int i = 0; i < 64; ++i) a = fmaf(w1[o * 64 + i], s[i], a);
        acc = fmaf(w2[o], fmaxf(a, 0.f), acc);
    }
    y[gid] = acc;
}

// ---------------- launch ----------------
extern "C" void kernel_launch(void* const* d_in, const int* in_sizes, int n_in,
                              void* d_out, int out_size, void* d_ws, size_t ws_size,
                              hipStream_t stream)
{
    const float* x       = (const float*)d_in[0];
    const float* c       = (const float*)d_in[1];
    const float* W_first = (const float*)d_in[2];
    const float* b_first = (const float*)d_in[3];
    const float* W_cin   = (const float*)d_in[4];
    const float* W_up    = (const float*)d_in[5];
    const float* Wd      = (const float*)d_in[6];
    const float* bd      = (const float*)d_in[7];
    const float* Wa      = (const float*)d_in[8];
    const float* Ws      = (const float*)d_in[9];
    const float* bs      = (const float*)d_in[10];
    const float* Wr      = (const float*)d_in[11];
    const float* br      = (const float*)d_in[12];
    const float* Wl1     = (const float*)d_in[13];
    const float* bl1     = (const float*)d_in[14];
    const float* Wl2     = (const float*)d_in[15];
    const float* bl2     = (const float*)d_in[16];

    char* base = (char*)d_ws;
    size_t off = 0;
    auto alloc = [&](size_t bytes) { char* p = base + off; off += (bytes + 255) & ~(size_t)255; return p; };

    u16* cup_hi = (u16*)alloc((size_t)2 * T_LEN * 96 * 2);
    u16* cup_lo = (u16*)alloc((size_t)2 * T_LEN * 96 * 2);
    u16* h0_hi  = (u16*)alloc((size_t)2 * T_LEN * 64 * 2);
    u16* h0_lo  = (u16*)alloc((size_t)2 * T_LEN * 64 * 2);
    u16* h1_hi  = (u16*)alloc((size_t)2 * T_LEN * 64 * 2);
    u16* h1_lo  = (u16*)alloc((size_t)2 * T_LEN * 64 * 2);
    float* skips = (float*)alloc((size_t)2 * T_LEN * 64 * 4);
    // scratch region: upsample chain first, then re-used for weight chunks
    char* S = alloc(7200000);
    float* c1 = (float*)(S);                       // 82KB
    float* u1 = (float*)(S + 81920);               // 328KB
    float* u2 = (float*)(S + 409600);              // 1.31MB
    float* u3 = (float*)(S + 1720320);             // 5.24MB  (ends 6.96MB)
    u16* WA = (u16*)(S);                           // 4.42MB (written after upfinal)
    u16* W2 = (u16*)(S + 4423680);                 // 0.98MB

    // upsample chain (t-major fp32), ending in t-major bf16 hi/lo c_up
    cin_kernel<<<(2 * 128 * 80 + 255) / 256, 256, 0, stream>>>(c, W_cin, c1);
    up_kernel<<<(2 * 512 * 80 + 255) / 256, 256, 0, stream>>>(c1, u1, W_up + 0, 128);
    up_kernel<<<(2 * 2048 * 80 + 255) / 256, 256, 0, stream>>>(u1, u2, W_up + 9, 512);
    up_kernel<<<(2 * 8192 * 80 + 255) / 256, 256, 0, stream>>>(u2, u3, W_up + 18, 2048);
    upfinal_kernel<<<(2 * T_LEN * 96 + 255) / 256, 256, 0, stream>>>(u3, W_up + 27, cup_hi, cup_lo);

    // weight prep (overwrites S after upsample chain; stream-ordered)
    prep_wmain<<<(NLAYERS * 9 * 8 * 64 + 255) / 256, 256, 0, stream>>>(Wd, Wa, WA);
    prep_wsr<<<(NLAYERS * 2 * 8 * 64 + 255) / 256, 256, 0, stream>>>(Ws, Wr, W2);

    first_kernel<<<(2 * T_LEN * 64) / 256, 256, 0, stream>>>(x, W_first, b_first, h0_hi, h0_lo);

    u16* hin_hi = h0_hi; u16* hin_lo = h0_lo;
    u16* hout_hi = h1_hi; u16* hout_lo = h1_lo;
    for (int l_ = 0; l_ < NLAYERS; ++l_) {
        int d = 1 << (l_ % 10);
        layer_kernel<<<dim3(T_LEN / 128, 2), 256, 0, stream>>>(
            hin_hi, hin_lo, hout_hi, hout_lo, skips, cup_hi, cup_lo,
            WA + (size_t)l_ * 9 * 8192, W2 + (size_t)l_ * 2 * 8192,
            bd + l_ * 128, bs + l_ * 64, br + l_ * 64, d, (l_ == 0) ? 1 : 0);
        u16* th = hin_hi; u16* tl = hin_lo;
        hin_hi = hout_hi; hin_lo = hout_lo;
        hout_hi = th; hout_lo = tl;
    }
    final_kernel<<<(2 * T_LEN) / 256, 256, 0, stream>>>(skips, Wl1, bl1, Wl2, bl2, (float*)d_out);
}